// Round 11
// baseline (128.927 us; speedup 1.0000x reference)
//
#include <hip/hip_runtime.h>
#include <hip/hip_bf16.h>

#define Bn 8
#define Nn 1024
#define Dn 256
#define Hn 4
#define HOn 64
#define Tn 5
#define WTR 80   // logical WP rows per head: 64 W^T cols + 10 Wa rows + 6 zero pad

typedef short bf16x8 __attribute__((ext_vector_type(8)));
typedef float f32x4 __attribute__((ext_vector_type(4)));

__device__ __forceinline__ float b2f(unsigned short u) {
    unsigned x = ((unsigned)u) << 16;
    float f;
    __builtin_memcpy(&f, &x, 4);
    return f;
}
__device__ __forceinline__ unsigned bfr(float f) {
    unsigned u;
    __builtin_memcpy(&u, &f, 4);
    return (u + 0x7FFFu + ((u >> 16) & 1u)) >> 16;
}
__device__ __forceinline__ unsigned short f2b(float f) { return (unsigned short)bfr(f); }

__device__ __forceinline__ float fast_exp2(float x) {
#if __has_builtin(__builtin_amdgcn_exp2f)
    return __builtin_amdgcn_exp2f(x);
#else
    float r;
    asm("v_exp_f32 %0, %1" : "=v"(r) : "v"(x));
    return r;
#endif
}

// ---------- fallback: signal "workspace too small" with out = 100.0 ----------
__global__ __launch_bounds__(256) void k_signal(float* __restrict__ out, int n) {
    int i = blockIdx.x * 256 + threadIdx.x;
    if (i < n) out[i] = 100.0f;
}

// ---------- kernel 0: WP in MFMA-FRAGMENT ORDER (R24, unchanged) ----------
__global__ __launch_bounds__(256) void k_transpose_w(const float* __restrict__ W,
                                                     const float* __restrict__ a_src,
                                                     const float* __restrict__ a_dst,
                                                     unsigned short* __restrict__ WP) {
    __shared__ float tile[64][65];    // [d_local][e]
    __shared__ float arow_s[10][64];  // [t][d_local]
    int h = blockIdx.x >> 2;
    int d0 = (blockIdx.x & 3) * 64;
    int c0 = threadIdx.x & 63;
    int r0 = threadIdx.x >> 6;  // 0..3
#pragma unroll
    for (int r = 0; r < 16; r++) {
        int d = r * 4 + r0;
        tile[d][c0] = W[((size_t)(h * Dn + d0 + d)) * HOn + c0];  // coalesced over e
    }
    __syncthreads();
    // a-row dots: arow_s[t][d_local] = sum_e W^T[d][e] * a[t][e]
    for (int t = r0; t < 2 * Tn; t += 4) {
        const float* av = (t < Tn) ? (a_src + (h * Tn + t) * HOn)
                                   : (a_dst + (h * Tn + t - Tn) * HOn);
        float s = 0.f;
#pragma unroll
        for (int e = 0; e < HOn; e++) s += tile[c0][e] * av[e];
        arow_s[t][c0] = s;
    }
    __syncthreads();
    // fragment-order writes: this block covers kc in {kcb, kcb+1}
    int kcb = d0 >> 5;
#pragma unroll
    for (int it = 0; it < 3; it++) {
        int idx = threadIdx.x + it * 256;
        if (idx < 640) {  // 2 kc' x 5 et x 64 lanes
            int kcp = idx / 320;
            int rem = idx % 320;
            int et = rem >> 6;
            int ln = rem & 63;
            int quad = ln >> 4, l15 = ln & 15;
            int dl = kcp * 32 + quad * 8;
            int row = et * 16 + l15;
            union { bf16x8 v; unsigned short u[8]; } ov;
#pragma unroll
            for (int m = 0; m < 8; m++) {
                float x = (row < 64) ? tile[dl + m][row]
                                     : ((row < 74) ? arow_s[row - 64][dl + m] : 0.f);
                ov.u[m] = f2b(x);
            }
            *(bf16x8*)(WP + ((((size_t)h * 8 + kcb + kcp) * 5 + et) * 64 + ln) * 8) = ov.v;
        }
    }
}

// ---------- kernel 1: h^P = W^T x X^T via MFMA (R24 exact, adjp packing restored) ----------
__global__ __launch_bounds__(256) void k_proj(const float* __restrict__ X,
                                              const unsigned short* __restrict__ WP,
                                              const int* __restrict__ adj,
                                              unsigned short* __restrict__ hP,
                                              float* __restrict__ e_src,
                                              float* __restrict__ e_dst,
                                              unsigned* __restrict__ adjp) {
    __shared__ unsigned short xs[16][264];       // X tile bf16, row pad 8 (16-B aligned rows)
    __shared__ unsigned short ptile[4][64][24];  // per-wave transpose tile
    int tid = threadIdx.x;
    int w = tid >> 6;
    int lane = tid & 63;
    int quad = lane >> 4;
    int l15 = lane & 15;
    int b = blockIdx.x >> 6;
    int i0 = (blockIdx.x & 63) * 16;
    int h = w;
    int bh = b * Hn + h;

    // pack this block's 16 adj rows to u8 (coalesced int4 loads / u32 stores)
    {
        const int* arow = adj + ((size_t)(b * Nn + i0)) * Nn;
        unsigned* aout = adjp + ((size_t)(b * Nn + i0)) * Nn / 4;
#pragma unroll 4
        for (int k = 0; k < 16; k++) {
            int idx = tid + k * 256;
            int4 v = *(const int4*)(arow + (size_t)idx * 4);
            unsigned pk = (unsigned)(v.x & 0xFF) | ((unsigned)(v.y & 0xFF) << 8) |
                          ((unsigned)(v.z & 0xFF) << 16) | ((unsigned)(v.w & 0xFF) << 24);
            aout[idx] = pk;
        }
    }

    // stage X tile once: 256 threads x float4 = 4 KB contiguous per instruction
#pragma unroll
    for (int it = 0; it < 4; it++) {
        int row = it * 4 + (tid >> 6);
        int col = (tid & 63) * 4;
        float4 v = *(const float4*)(X + ((size_t)(b * Nn + i0 + row)) * Dn + col);
        __hip_bfloat162 h0 = __float22bfloat162_rn(make_float2(v.x, v.y));
        __hip_bfloat162 h1 = __float22bfloat162_rn(make_float2(v.z, v.w));
        unsigned u0, u1;
        __builtin_memcpy(&u0, &h0, 4);
        __builtin_memcpy(&u1, &h1, 4);
        unsigned* dst = (unsigned*)&xs[row][col];
        dst[0] = u0;
        dst[1] = u1;
    }
    __syncthreads();

    // B-fragments from LDS (scatter is cheap here)
    bf16x8 Bx[8];
#pragma unroll
    for (int kc = 0; kc < 8; kc++)
        Bx[kc] = *(const bf16x8*)(&xs[l15][kc * 32 + quad * 8]);

    f32x4 acc[5] = {{0.f, 0.f, 0.f, 0.f}, {0.f, 0.f, 0.f, 0.f}, {0.f, 0.f, 0.f, 0.f},
                    {0.f, 0.f, 0.f, 0.f}, {0.f, 0.f, 0.f, 0.f}};
    const unsigned short* wbase = WP + (size_t)h * 8 * 5 * 64 * 8;
#pragma unroll
    for (int kc = 0; kc < 8; kc++) {
#pragma unroll
        for (int et = 0; et < 5; et++) {
            bf16x8 Aw = *(const bf16x8*)(wbase + (((size_t)kc * 5 + et) * 64 + lane) * 8);
            acc[et] = __builtin_amdgcn_mfma_f32_16x16x32_bf16(Aw, Bx[kc], acc[et], 0, 0, 0);
        }
    }

    // h tile -> per-wave LDS (bf16), then 2 coalesced 1-KB fragment-order stores (R23)
#pragma unroll
    for (int et = 0; et < 4; et++) {
#pragma unroll
        for (int reg = 0; reg < 4; reg++) {
            int e = et * 16 + quad * 4 + reg;
            ptile[w][e][l15] = f2b(acc[et][reg]);  // ds_write_b16, own-wave tile
        }
    }
    __builtin_amdgcn_s_waitcnt(0);  // ds_writes of own wave complete (lgkm in-order)
    {
        int jb = i0 >> 4;
        int e_lo = lane >> 5;          // 0..1
        int l15v = (lane >> 1) & 15;   // 0..15
        int q2 = lane & 1;             // 0..1
#pragma unroll
        for (int p = 0; p < 2; p++) {
            int et = 2 * p + e_lo;
            bf16x8 v = *(const bf16x8*)(&ptile[w][et * 16 + l15v][q2 * 8]);
            *(bf16x8*)(hP + (((size_t)bh * 64 + jb) * 4 + et) * 256 + l15v * 16 + q2 * 8) = v;
        }
    }
#pragma unroll
    for (int reg = 0; reg < 4; reg++) {
        int t = quad * 4 + reg;
        if (t < Tn)
            e_src[((size_t)bh * Tn + t) * Nn + i0 + l15] = acc[4][reg] * 1.4426950408889634f;
        else if (t < 2 * Tn)
            e_dst[((size_t)bh * Tn + (t - Tn)) * Nn + i0 + l15] = acc[4][reg] * 1.4426950408889634f;
    }
}

// ---------- kernel 2: fused attention — R27: register-cndmask ed select (ed_lds deleted) --
// grid: B * (N/16) = 512 blocks x 512 threads (8 waves); wave = (head = w&3, j-half = w>>2).
// R27 theory: R24's remaining stall budget includes ~6-8 us of ed LDS-gather latency
// (~120cy/row, exp-dependent, shallow compiler lookahead at VGPR 56). R18 picked gathers
// over cndmask when pass-1 carried clamp + expf-mul + explicit masking; all three are
// gone now, so the trade flips back: select ed from the prefetched edc[5] REGISTERS via
// a 4-cndmask chain (pipelined VALU, no latency), mask via es2 slot-0 = -3e38 sentinel
// (absorbs any finite d; leaky+exp2 -> exact 0; no compare needed). Deletes ed_lds
// (-25.6 KB -> LDS 37,376), its 10 commit-writes/chunk, and both gathers/pair.
// Kept from R24 (measured best, 122.8): u16 adjp loads + full-chunk adj prefetch (R20);
// hP fragment-order PV B-loads (R23); p_lds + macc overlay; l via 5th MFMA tile (R13);
// grid/block shape optimum (R17); no rotation/setprio (R21); no asm prefetch (R22 spill).
__global__ __launch_bounds__(512) void k_attn(const unsigned char* __restrict__ adjp,
                                              const float* __restrict__ e_src,
                                              const float* __restrict__ e_dst,
                                              const unsigned short* __restrict__ hP,
                                              const float* __restrict__ bias,
                                              const float* __restrict__ gamma,
                                              const float* __restrict__ beta,
                                              float* __restrict__ out) {
    __shared__ __align__(16) unsigned short p_lds[8][16][136];  // 34,816 B
    __shared__ float es2[4][16][8];  // [hh][row][a]; slot 0 = -3e38 mask sentinel
    __shared__ float l_lds[8][16];
    float* macc = (float*)&p_lds[4][0][0];  // [4 hh][16 r][64 e] f32 overlay (16,384 B)

    int tid = threadIdx.x;
    int w = tid >> 6;
    int lane = tid & 63;
    int quad = lane >> 4;
    int l15 = lane & 15;
    int hh = w & 3;
    int half = w >> 2;
    int b = blockIdx.x >> 6;
    int i0 = (blockIdx.x & 63) * 16;
    int bh = b * Hn + hh;
    int J0 = half * 512;

    const unsigned char* adj_base = adjp + ((size_t)(b * Nn + i0)) * Nn + J0;
    const float* edst = e_dst + (size_t)bh * Tn * Nn + J0;
    const unsigned short* hPb = hP + (size_t)bh * 64 * 1024;  // [jb][et][l15][q2][m]

    int c0 = 2 * lane;

    f32x4 acc[4] = {{0.f, 0.f, 0.f, 0.f}, {0.f, 0.f, 0.f, 0.f},
                    {0.f, 0.f, 0.f, 0.f}, {0.f, 0.f, 0.f, 0.f}};
    f32x4 accl = {0.f, 0.f, 0.f, 0.f};  // l row-sums via MFMA with B = ones
    bf16x8 ONES;
    {
        short o = (short)0x3F80;  // bf16 1.0
        ONES = (bf16x8){o, o, o, o, o, o, o, o};
    }

    // prologue: chunk 0's full 16 adj rows + ed into regs
    unsigned adjC[16], adjN[16];
#pragma unroll
    for (int r = 0; r < 16; r++)
        adjC[r] = *(const unsigned short*)(adj_base + (size_t)r * Nn + c0);
    float2 edc[Tn], edn[Tn];
#pragma unroll
    for (int t = 0; t < Tn; t++) edc[t] = *(const float2*)(edst + t * Nn + c0);

    // es2[hh][row][a] staging (waves 0-3): slot 0 = -3e38 MASK sentinel, 1..5 = e_src
    if (w < 4) {
        const float* esrc = e_src + (size_t)bh * Tn * Nn;
#pragma unroll
        for (int idx = lane; idx < 96; idx += 64) {
            int t = idx >> 4, row = idx & 15;
            es2[w][row][t] = t ? esrc[(t - 1) * Nn + i0 + row] : -3e38f;
        }
    }
    __syncthreads();

// pass-1: p = exp2(leakyrelu(es2[row][a] + ed_sel)); a=0 -> es = -3e38 absorbs any d ->
// exp2 -> exact 0 (mask free). es: LDS broadcast (<=6 distinct banks, conflict-free);
// ed: register cndmask chain on edc (pipelined VALU, no LDS latency).
#define P1ROW(ROW, AV)                                                          \
    {                                                                           \
        int a0 = (int)((AV) & 0xFFu);                                           \
        int a1 = (int)((AV) >> 8);                                              \
        float e0 = es2[hh][ROW][a0];                                            \
        float e1 = es2[hh][ROW][a1];                                            \
        int t0 = a0 - 1, t1 = a1 - 1;                                           \
        float d0 = edc[0].x, d1 = edc[0].y;                                     \
        d0 = (t0 == 1) ? edc[1].x : d0; d1 = (t1 == 1) ? edc[1].y : d1;         \
        d0 = (t0 == 2) ? edc[2].x : d0; d1 = (t1 == 2) ? edc[2].y : d1;         \
        d0 = (t0 == 3) ? edc[3].x : d0; d1 = (t1 == 3) ? edc[3].y : d1;         \
        d0 = (t0 == 4) ? edc[4].x : d0; d1 = (t1 == 4) ? edc[4].y : d1;         \
        float x0 = e0 + d0; x0 = fmaxf(x0, 0.01f * x0);                         \
        float x1 = e1 + d1; x1 = fmaxf(x1, 0.01f * x1);                         \
        float p0 = fast_exp2(x0);                                               \
        float p1 = fast_exp2(x1);                                               \
        __hip_bfloat162 pp = __float22bfloat162_rn(make_float2(p0, p1));        \
        unsigned pu; __builtin_memcpy(&pu, &pp, 4);                             \
        *(unsigned*)(&p_lds[w][ROW][2 * lane]) = pu;                            \
    }

#pragma unroll 1
    for (int c = 0; c < 4; c++) {
        int jc = c * 128;  // relative to J0
        // next chunk's FULL adj row set + ed into regs (R20) — consumed next iteration,
        // so pass-1 + PV of this chunk (~600+cy) cover the L2/HBM latency.
        if (c < 3) {
#pragma unroll
            for (int r = 0; r < 16; r++)
                adjN[r] = *(const unsigned short*)(adj_base + (size_t)r * Nn + jc + 128 + c0);
#pragma unroll
            for (int t = 0; t < Tn; t++)
                edn[t] = *(const float2*)(edst + t * Nn + jc + 128 + c0);
        }
        // pass-1 over all 16 rows from adjC regs
#pragma unroll
        for (int r = 0; r < 16; r++) P1ROW(r, adjC[r]);
        // PV via MFMA: A = P (own-wave LDS, b128); B = hP fragment-order (coalesced);
        // 5th tile (B=ones) accumulates l row-sums
#pragma unroll
        for (int k = 0; k < 4; k++) {
            bf16x8 Afr = *(const bf16x8*)(&p_lds[w][l15][k * 32 + quad * 8]);
            accl = __builtin_amdgcn_mfma_f32_16x16x32_bf16(Afr, ONES, accl, 0, 0, 0);
            int jb = ((J0 + jc + k * 32) >> 4) + (quad >> 1);
#pragma unroll
            for (int et = 0; et < 4; et++) {
                bf16x8 Bf = *(const bf16x8*)(hPb + ((size_t)jb * 4 + et) * 256 +
                                             l15 * 16 + (quad & 1) * 8);
                acc[et] = __builtin_amdgcn_mfma_f32_16x16x32_bf16(Afr, Bf, acc[et], 0, 0, 0);
            }
        }
        // promote prefetched adj + ed
        if (c < 3) {
#pragma unroll
            for (int r = 0; r < 16; r++) adjC[r] = adjN[r];
#pragma unroll
            for (int t = 0; t < Tn; t++) edc[t] = edn[t];
        }
    }
#undef P1ROW

    // l: accl[reg] (any l15 col) = row-sum for row quad*4+reg
    if (l15 == 0) {
#pragma unroll
        for (int reg = 0; reg < 4; reg++) l_lds[w][quad * 4 + reg] = accl[reg];
    }
    __syncthreads();  // all waves done with p_lds (MFMA reads) before macc overlay
    if (w >= 4) {
#pragma unroll
        for (int et = 0; et < 4; et++)
#pragma unroll
            for (int reg = 0; reg < 4; reg++)
                macc[((hh * 16) + quad * 4 + reg) * 64 + et * 16 + l15] = acc[et][reg];
    }
    __syncthreads();
    if (w >= 4) return;

    // merge + epilogue: /l, +bias, relu, +h, LayerNorm over HO, store f32
    float bv[4], gv[4], bev[4];
#pragma unroll
    for (int et = 0; et < 4; et++) {
        int e = et * 16 + l15;
        bv[et] = bias[hh * HOn + e];
        gv[et] = gamma[hh * HOn + e];
        bev[et] = beta[hh * HOn + e];
    }
    int jbe = i0 >> 4;
#pragma unroll
    for (int reg = 0; reg < 4; reg++) {
        int r = quad * 4 + reg;
        int i = i0 + r;
        float lw = l_lds[w][r] + l_lds[w + 4][r];
        float linv = 1.f / fmaxf(lw, 1e-30f);
        float dv[4];
        float s = 0.f, ss = 0.f;
        int q2 = r >> 3, m = r & 7;
#pragma unroll
        for (int et = 0; et < 4; et++) {
            int e = et * 16 + l15;
            float v = (acc[et][reg] + macc[((hh * 16) + r) * 64 + e]) * linv + bv[et];
            v = (v > 0.f) ? v : 0.f;
            v += b2f(hPb[((size_t)jbe * 4 + et) * 256 + l15 * 16 + q2 * 8 + m]);  // residual h
            dv[et] = v;
            s += v;
            ss += v * v;
        }
#pragma unroll
        for (int off = 8; off; off >>= 1) {
            s += __shfl_xor(s, off);
            ss += __shfl_xor(ss, off);
        }
        float mean = s * (1.f / 64.f);
        float var = ss * (1.f / 64.f) - mean * mean;
        float rstd = rsqrtf(var + 1e-6f);
#pragma unroll
        for (int et = 0; et < 4; et++) {
            int e = et * 16 + l15;
            float o = (dv[et] - mean) * rstd * gv[et] + bev[et];
            out[((size_t)(b * Nn + i)) * (Hn * HOn) + hh * HOn + e] = o;
        }
    }
}

extern "C" void kernel_launch(void* const* d_in, const int* in_sizes, int n_in,
                              void* d_out, int out_size, void* d_ws, size_t ws_size,
                              hipStream_t stream) {
    const float* X = (const float*)d_in[0];        // nodes_embed f32 [B,N,D]
    const int* adj = (const int*)d_in[1];          // node_adj int32 [B,N,N]
    const float* W = (const float*)d_in[2];        // [H,D,HO] f32
    const float* a_src = (const float*)d_in[3];    // [H,T,HO] f32
    const float* a_dst = (const float*)d_in[4];    // [H,T,HO] f32
    const float* bias = (const float*)d_in[5];     // [H,HO] f32
    const float* gamma = (const float*)d_in[6];    // [H,HO] f32
    const float* beta = (const float*)d_in[7];     // [H,HO] f32
    float* out = (float*)d_out;                    // [B,N,H*HO] f32

    char* ws = (char*)d_ws;
    size_t off = 0;
    unsigned short* hP = (unsigned short*)(ws + off);  off += (size_t)Bn * Hn * Nn * HOn * 2;  // 4 MB
    unsigned short* WP = (unsigned short*)(ws + off);  off += (size_t)Hn * WTR * Dn * 2;       // 160 KB
    float* e_src = (float*)(ws + off);                 off += (size_t)Bn * Hn * Tn * Nn * 4;   // 640 KB
    float* e_dst = (float*)(ws + off);                 off += (size_t)Bn * Hn * Tn * Nn * 4;   // 640 KB
    unsigned char* adjp = (unsigned char*)(ws + off);  off += (size_t)Bn * Nn * Nn;            // 8 MB

    if (ws_size < off) {
        k_signal<<<(out_size + 255) / 256, 256, 0, stream>>>(out, out_size);
        return;
    }

    k_transpose_w<<<Hn * (Dn / 64), 256, 0, stream>>>(W, a_src, a_dst, WP);
    k_proj<<<Bn * (Nn / 16), 256, 0, stream>>>(X, WP, adj, hP, e_src, e_dst, (unsigned*)adjp);
    k_attn<<<Bn * (Nn / 16), 512, 0, stream>>>(adjp, e_src, e_dst, hP, bias, gamma, beta, out);
}

// Round 12
// 125.251 us; speedup vs baseline: 1.0293x; 1.0293x over previous
//
#include <hip/hip_runtime.h>
#include <hip/hip_bf16.h>

#define Bn 8
#define Nn 1024
#define Dn 256
#define Hn 4
#define HOn 64
#define Tn 5
#define WTR 80   // logical WP rows per head: 64 W^T cols + 10 Wa rows + 6 zero pad
#define EDS 128  // ed_lds row stride (words); stride%32==0 -> bank=c0%32, 2 lanes/bank = free

typedef short bf16x8 __attribute__((ext_vector_type(8)));
typedef float f32x4 __attribute__((ext_vector_type(4)));

__device__ __forceinline__ float b2f(unsigned short u) {
    unsigned x = ((unsigned)u) << 16;
    float f;
    __builtin_memcpy(&f, &x, 4);
    return f;
}
__device__ __forceinline__ unsigned bfr(float f) {
    unsigned u;
    __builtin_memcpy(&u, &f, 4);
    return (u + 0x7FFFu + ((u >> 16) & 1u)) >> 16;
}
__device__ __forceinline__ unsigned short f2b(float f) { return (unsigned short)bfr(f); }

__device__ __forceinline__ float fast_exp2(float x) {
#if __has_builtin(__builtin_amdgcn_exp2f)
    return __builtin_amdgcn_exp2f(x);
#else
    float r;
    asm("v_exp_f32 %0, %1" : "=v"(r) : "v"(x));
    return r;
#endif
}

// ---------- fallback: signal "workspace too small" with out = 100.0 ----------
__global__ __launch_bounds__(256) void k_signal(float* __restrict__ out, int n) {
    int i = blockIdx.x * 256 + threadIdx.x;
    if (i < n) out[i] = 100.0f;
}

// ---------- kernel 0: WP in MFMA-FRAGMENT ORDER (R24) ----------
__global__ __launch_bounds__(256) void k_transpose_w(const float* __restrict__ W,
                                                     const float* __restrict__ a_src,
                                                     const float* __restrict__ a_dst,
                                                     unsigned short* __restrict__ WP) {
    __shared__ float tile[64][65];    // [d_local][e]
    __shared__ float arow_s[10][64];  // [t][d_local]
    int h = blockIdx.x >> 2;
    int d0 = (blockIdx.x & 3) * 64;
    int c0 = threadIdx.x & 63;
    int r0 = threadIdx.x >> 6;  // 0..3
#pragma unroll
    for (int r = 0; r < 16; r++) {
        int d = r * 4 + r0;
        tile[d][c0] = W[((size_t)(h * Dn + d0 + d)) * HOn + c0];  // coalesced over e
    }
    __syncthreads();
    // a-row dots: arow_s[t][d_local] = sum_e W^T[d][e] * a[t][e]
    for (int t = r0; t < 2 * Tn; t += 4) {
        const float* av = (t < Tn) ? (a_src + (h * Tn + t) * HOn)
                                   : (a_dst + (h * Tn + t - Tn) * HOn);
        float s = 0.f;
#pragma unroll
        for (int e = 0; e < HOn; e++) s += tile[c0][e] * av[e];
        arow_s[t][c0] = s;
    }
    __syncthreads();
    // fragment-order writes: this block covers kc in {kcb, kcb+1}
    int kcb = d0 >> 5;
#pragma unroll
    for (int it = 0; it < 3; it++) {
        int idx = threadIdx.x + it * 256;
        if (idx < 640) {  // 2 kc' x 5 et x 64 lanes
            int kcp = idx / 320;
            int rem = idx % 320;
            int et = rem >> 6;
            int ln = rem & 63;
            int quad = ln >> 4, l15 = ln & 15;
            int dl = kcp * 32 + quad * 8;
            int row = et * 16 + l15;
            union { bf16x8 v; unsigned short u[8]; } ov;
#pragma unroll
            for (int m = 0; m < 8; m++) {
                float x = (row < 64) ? tile[dl + m][row]
                                     : ((row < 74) ? arow_s[row - 64][dl + m] : 0.f);
                ov.u[m] = f2b(x);
            }
            *(bf16x8*)(WP + ((((size_t)h * 8 + kcb + kcp) * 5 + et) * 64 + ln) * 8) = ov.v;
        }
    }
}

// ---------- kernel 1: h^P = W^T x X^T via MFMA (R24 structure) ----------
__global__ __launch_bounds__(256) void k_proj(const float* __restrict__ X,
                                              const unsigned short* __restrict__ WP,
                                              const int* __restrict__ adj,
                                              unsigned short* __restrict__ hP,
                                              float* __restrict__ e_src,
                                              float* __restrict__ e_dst,
                                              unsigned* __restrict__ adjp) {
    __shared__ unsigned short xs[16][264];       // X tile bf16, row pad 8 (16-B aligned rows)
    __shared__ unsigned short ptile[4][64][24];  // per-wave transpose tile
    int tid = threadIdx.x;
    int w = tid >> 6;
    int lane = tid & 63;
    int quad = lane >> 4;
    int l15 = lane & 15;
    int b = blockIdx.x >> 6;
    int i0 = (blockIdx.x & 63) * 16;
    int h = w;
    int bh = b * Hn + h;

    // pack this block's 16 adj rows to u8 (coalesced int4 loads / u32 stores)
    {
        const int* arow = adj + ((size_t)(b * Nn + i0)) * Nn;
        unsigned* aout = adjp + ((size_t)(b * Nn + i0)) * Nn / 4;
#pragma unroll 4
        for (int k = 0; k < 16; k++) {
            int idx = tid + k * 256;
            int4 v = *(const int4*)(arow + (size_t)idx * 4);
            unsigned pk = (unsigned)(v.x & 0xFF) | ((unsigned)(v.y & 0xFF) << 8) |
                          ((unsigned)(v.z & 0xFF) << 16) | ((unsigned)(v.w & 0xFF) << 24);
            aout[idx] = pk;
        }
    }

    // stage X tile once: 256 threads x float4 = 4 KB contiguous per instruction
#pragma unroll
    for (int it = 0; it < 4; it++) {
        int row = it * 4 + (tid >> 6);
        int col = (tid & 63) * 4;
        float4 v = *(const float4*)(X + ((size_t)(b * Nn + i0 + row)) * Dn + col);
        __hip_bfloat162 h0 = __float22bfloat162_rn(make_float2(v.x, v.y));
        __hip_bfloat162 h1 = __float22bfloat162_rn(make_float2(v.z, v.w));
        unsigned u0, u1;
        __builtin_memcpy(&u0, &h0, 4);
        __builtin_memcpy(&u1, &h1, 4);
        unsigned* dst = (unsigned*)&xs[row][col];
        dst[0] = u0;
        dst[1] = u1;
    }
    __syncthreads();

    // B-fragments from LDS (scatter is cheap here)
    bf16x8 Bx[8];
#pragma unroll
    for (int kc = 0; kc < 8; kc++)
        Bx[kc] = *(const bf16x8*)(&xs[l15][kc * 32 + quad * 8]);

    f32x4 acc[5] = {{0.f, 0.f, 0.f, 0.f}, {0.f, 0.f, 0.f, 0.f}, {0.f, 0.f, 0.f, 0.f},
                    {0.f, 0.f, 0.f, 0.f}, {0.f, 0.f, 0.f, 0.f}};
    const unsigned short* wbase = WP + (size_t)h * 8 * 5 * 64 * 8;
#pragma unroll
    for (int kc = 0; kc < 8; kc++) {
#pragma unroll
        for (int et = 0; et < 5; et++) {
            bf16x8 Aw = *(const bf16x8*)(wbase + (((size_t)kc * 5 + et) * 64 + lane) * 8);
            acc[et] = __builtin_amdgcn_mfma_f32_16x16x32_bf16(Aw, Bx[kc], acc[et], 0, 0, 0);
        }
    }

    // h tile -> per-wave LDS (bf16), then 2 coalesced 1-KB fragment-order stores (R23)
#pragma unroll
    for (int et = 0; et < 4; et++) {
#pragma unroll
        for (int reg = 0; reg < 4; reg++) {
            int e = et * 16 + quad * 4 + reg;
            ptile[w][e][l15] = f2b(acc[et][reg]);  // ds_write_b16, own-wave tile
        }
    }
    __builtin_amdgcn_s_waitcnt(0);  // ds_writes of own wave complete (lgkm in-order)
    {
        int jb = i0 >> 4;
        int e_lo = lane >> 5;          // 0..1
        int l15v = (lane >> 1) & 15;   // 0..15
        int q2 = lane & 1;             // 0..1
#pragma unroll
        for (int p = 0; p < 2; p++) {
            int et = 2 * p + e_lo;
            bf16x8 v = *(const bf16x8*)(&ptile[w][et * 16 + l15v][q2 * 8]);
            *(bf16x8*)(hP + (((size_t)bh * 64 + jb) * 4 + et) * 256 + l15v * 16 + q2 * 8) = v;
        }
    }
#pragma unroll
    for (int reg = 0; reg < 4; reg++) {
        int t = quad * 4 + reg;
        if (t < Tn)
            e_src[((size_t)bh * Tn + t) * Nn + i0 + l15] = acc[4][reg] * 1.4426950408889634f;
        else if (t < 2 * Tn)
            e_dst[((size_t)bh * Tn + (t - Tn)) * Nn + i0 + l15] = acc[4][reg] * 1.4426950408889634f;
    }
}

// ---------- kernel 2: fused attention — R24 (measured best, 122.8 us) ----------
// grid: B * (N/16) = 512 blocks x 512 threads (8 waves); wave = (head = w&3, j-half = w>>2).
// Final configuration after 10 theory-driven rounds. Wins: LDS-gather pass-1 + sentinels
// (R18); full-chunk adj+ed reg prefetch (R20); hP fragment-order PV B-loads — the big
// one, line-transaction divergence fix (R23); X-stage + WP fragment-order in k_proj
// (R24). Refuted & reverted: asm/C-level Bf prefetch (R19/R22, allocator-refused);
// rotation+setprio (R21); in-register P (R25); raw-adj direct reads (R26); register-
// cndmask ed select (R27). Remaining k_attn budget: ~7 us PV L2 traffic (irreducible),
// ~4 us VALU/trans, ~3 us TA line-touches (coalesced optimum), rest latency slack that
// 7 scheduling attacks could not compress.
__global__ __launch_bounds__(512) void k_attn(const unsigned char* __restrict__ adjp,
                                              const float* __restrict__ e_src,
                                              const float* __restrict__ e_dst,
                                              const unsigned short* __restrict__ hP,
                                              const float* __restrict__ bias,
                                              const float* __restrict__ gamma,
                                              const float* __restrict__ beta,
                                              float* __restrict__ out) {
    __shared__ __align__(16) unsigned short p_lds[8][16][136];  // 34,816 B
    __shared__ float es2[4][16][8];                             // [hh][row][a], a=0 -> 0.0
    __shared__ float l_lds[8][16];
    __shared__ __align__(16) float ed_lds[8][6 * EDS];          // per-wave, row 0 sentinel
    float* macc = (float*)&p_lds[4][0][0];  // [4 hh][16 r][64 e] f32 overlay (16,384 B)

    int tid = threadIdx.x;
    int w = tid >> 6;
    int lane = tid & 63;
    int quad = lane >> 4;
    int l15 = lane & 15;
    int hh = w & 3;
    int half = w >> 2;
    int b = blockIdx.x >> 6;
    int i0 = (blockIdx.x & 63) * 16;
    int bh = b * Hn + hh;
    int J0 = half * 512;

    const unsigned char* adj_base = adjp + ((size_t)(b * Nn + i0)) * Nn + J0;
    const float* edst = e_dst + (size_t)bh * Tn * Nn + J0;
    const unsigned short* hPb = hP + (size_t)bh * 64 * 1024;  // [jb][et][l15][q2][m]

    int c0 = 2 * lane;
    float* edw = &ed_lds[w][0];

    f32x4 acc[4] = {{0.f, 0.f, 0.f, 0.f}, {0.f, 0.f, 0.f, 0.f},
                    {0.f, 0.f, 0.f, 0.f}, {0.f, 0.f, 0.f, 0.f}};
    f32x4 accl = {0.f, 0.f, 0.f, 0.f};  // l row-sums via MFMA with B = ones
    bf16x8 ONES;
    {
        short o = (short)0x3F80;  // bf16 1.0
        ONES = (bf16x8){o, o, o, o, o, o, o, o};
    }

    // ed sentinel row (a = 0): exp2(leaky(-3e38)) == 0 -> masked p = 0
    edw[c0] = -3e38f;
    edw[c0 + 1] = -3e38f;

    // prologue: chunk 0's full 16 adj rows + ed into regs
    unsigned adjC[16], adjN[16];
#pragma unroll
    for (int r = 0; r < 16; r++)
        adjC[r] = *(const unsigned short*)(adj_base + (size_t)r * Nn + c0);
    float2 edr[Tn];
#pragma unroll
    for (int t = 0; t < Tn; t++) edr[t] = *(const float2*)(edst + t * Nn + c0);

    // es2[hh][row][a] staging (waves 0-3): slot 0 = 0.0 sentinel, slots 1..5 = e_src
    if (w < 4) {
        const float* esrc = e_src + (size_t)bh * Tn * Nn;
#pragma unroll
        for (int idx = lane; idx < 96; idx += 64) {
            int t = idx >> 4, row = idx & 15;
            es2[w][row][t] = t ? esrc[(t - 1) * Nn + i0 + row] : 0.f;
        }
    }
    __syncthreads();

// pass-1: p = exp2(leakyrelu(es2[row][a] + ed_lds[a][col])), sentinels make masked -> 0.
// es: LDS broadcast (6 distinct banks, conflict-free); ed: EDS=128 gather (2-way, free).
#define P1ROW(ROW, AV)                                                          \
    {                                                                           \
        int a0 = (int)((AV) & 0xFFu);                                           \
        int a1 = (int)((AV) >> 8);                                              \
        float e0 = es2[hh][ROW][a0];                                            \
        float e1 = es2[hh][ROW][a1];                                            \
        float d0 = edw[a0 * EDS + c0];                                          \
        float d1 = edw[a1 * EDS + c0 + 1];                                      \
        float x0 = e0 + d0; x0 = fmaxf(x0, 0.01f * x0);                         \
        float x1 = e1 + d1; x1 = fmaxf(x1, 0.01f * x1);                         \
        float p0 = fast_exp2(x0);                                               \
        float p1 = fast_exp2(x1);                                               \
        __hip_bfloat162 pp = __float22bfloat162_rn(make_float2(p0, p1));        \
        unsigned pu; __builtin_memcpy(&pu, &pp, 4);                             \
        *(unsigned*)(&p_lds[w][ROW][2 * lane]) = pu;                            \
    }

#pragma unroll 1
    for (int c = 0; c < 4; c++) {
        int jc = c * 128;  // relative to J0
        // commit this chunk's ed regs to LDS rows 1..5 (reads edr loaded a full chunk ago)
#pragma unroll
        for (int t = 0; t < Tn; t++) {
            int wi = (t + 1) * EDS + c0;
            edw[wi] = edr[t].x;
            edw[wi + 1] = edr[t].y;
        }
        // next chunk's FULL adj row set + ed (R20) — consumed next iteration,
        // so pass-1 + PV of this chunk (~600+cy) cover the L2/HBM latency.
        if (c < 3) {
#pragma unroll
            for (int r = 0; r < 16; r++)
                adjN[r] = *(const unsigned short*)(adj_base + (size_t)r * Nn + jc + 128 + c0);
#pragma unroll
            for (int t = 0; t < Tn; t++)
                edr[t] = *(const float2*)(edst + t * Nn + jc + 128 + c0);
        }
        // pass-1 over all 16 rows from adjC regs
#pragma unroll
        for (int r = 0; r < 16; r++) P1ROW(r, adjC[r]);
        // PV via MFMA: A = P (own-wave LDS, b128); B = hP fragment-order (coalesced);
        // 5th tile (B=ones) accumulates l row-sums
#pragma unroll
        for (int k = 0; k < 4; k++) {
            bf16x8 Afr = *(const bf16x8*)(&p_lds[w][l15][k * 32 + quad * 8]);
            accl = __builtin_amdgcn_mfma_f32_16x16x32_bf16(Afr, ONES, accl, 0, 0, 0);
            int jb = ((J0 + jc + k * 32) >> 4) + (quad >> 1);
#pragma unroll
            for (int et = 0; et < 4; et++) {
                bf16x8 Bf = *(const bf16x8*)(hPb + ((size_t)jb * 4 + et) * 256 +
                                             l15 * 16 + (quad & 1) * 8);
                acc[et] = __builtin_amdgcn_mfma_f32_16x16x32_bf16(Afr, Bf, acc[et], 0, 0, 0);
            }
        }
        // promote prefetched adj
        if (c < 3) {
#pragma unroll
            for (int r = 0; r < 16; r++) adjC[r] = adjN[r];
        }
    }
#undef P1ROW

    // l: accl[reg] (any l15 col) = row-sum for row quad*4+reg
    if (l15 == 0) {
#pragma unroll
        for (int reg = 0; reg < 4; reg++) l_lds[w][quad * 4 + reg] = accl[reg];
    }
    __syncthreads();  // all waves done with p_lds (MFMA reads) before macc overlay
    if (w >= 4) {
#pragma unroll
        for (int et = 0; et < 4; et++)
#pragma unroll
            for (int reg = 0; reg < 4; reg++)
                macc[((hh * 16) + quad * 4 + reg) * 64 + et * 16 + l15] = acc[et][reg];
    }
    __syncthreads();
    if (w >= 4) return;

    // merge + epilogue: /l, +bias, relu, +h, LayerNorm over HO, store f32
    float bv[4], gv[4], bev[4];
#pragma unroll
    for (int et = 0; et < 4; et++) {
        int e = et * 16 + l15;
        bv[et] = bias[hh * HOn + e];
        gv[et] = gamma[hh * HOn + e];
        bev[et] = beta[hh * HOn + e];
    }
    int jbe = i0 >> 4;
#pragma unroll
    for (int reg = 0; reg < 4; reg++) {
        int r = quad * 4 + reg;
        int i = i0 + r;
        float lw = l_lds[w][r] + l_lds[w + 4][r];
        float linv = 1.f / fmaxf(lw, 1e-30f);
        float dv[4];
        float s = 0.f, ss = 0.f;
        int q2 = r >> 3, m = r & 7;
#pragma unroll
        for (int et = 0; et < 4; et++) {
            int e = et * 16 + l15;
            float v = (acc[et][reg] + macc[((hh * 16) + r) * 64 + e]) * linv + bv[et];
            v = (v > 0.f) ? v : 0.f;
            v += b2f(hPb[((size_t)jbe * 4 + et) * 256 + l15 * 16 + q2 * 8 + m]);  // residual h
            dv[et] = v;
            s += v;
            ss += v * v;
        }
#pragma unroll
        for (int off = 8; off; off >>= 1) {
            s += __shfl_xor(s, off);
            ss += __shfl_xor(ss, off);
        }
        float mean = s * (1.f / 64.f);
        float var = ss * (1.f / 64.f) - mean * mean;
        float rstd = rsqrtf(var + 1e-6f);
#pragma unroll
        for (int et = 0; et < 4; et++) {
            int e = et * 16 + l15;
            float o = (dv[et] - mean) * rstd * gv[et] + bev[et];
            out[((size_t)(b * Nn + i)) * (Hn * HOn) + hh * HOn + e] = o;
        }
    }
}

extern "C" void kernel_launch(void* const* d_in, const int* in_sizes, int n_in,
                              void* d_out, int out_size, void* d_ws, size_t ws_size,
                              hipStream_t stream) {
    const float* X = (const float*)d_in[0];        // nodes_embed f32 [B,N,D]
    const int* adj = (const int*)d_in[1];          // node_adj int32 [B,N,N]
    const float* W = (const float*)d_in[2];        // [H,D,HO] f32
    const float* a_src = (const float*)d_in[3];    // [H,T,HO] f32
    const float* a_dst = (const float*)d_in[4];    // [H,T,HO] f32
    const float* bias = (const float*)d_in[5];     // [H,HO] f32
    const float* gamma = (const float*)d_in[6];    // [H,HO] f32
    const float* beta = (const float*)d_in[7];     // [H,HO] f32
    float* out = (float*)d_out;                    // [B,N,H*HO] f32

    char* ws = (char*)d_ws;
    size_t off = 0;
    unsigned short* hP = (unsigned short*)(ws + off);  off += (size_t)Bn * Hn * Nn * HOn * 2;  // 4 MB
    unsigned short* WP = (unsigned short*)(ws + off);  off += (size_t)Hn * WTR * Dn * 2;       // 160 KB
    float* e_src = (float*)(ws + off);                 off += (size_t)Bn * Hn * Tn * Nn * 4;   // 640 KB
    float* e_dst = (float*)(ws + off);                 off += (size_t)Bn * Hn * Tn * Nn * 4;   // 640 KB
    unsigned char* adjp = (unsigned char*)(ws + off);  off += (size_t)Bn * Nn * Nn;            // 8 MB

    if (ws_size < off) {
        k_signal<<<(out_size + 255) / 256, 256, 0, stream>>>(out, out_size);
        return;
    }

    k_transpose_w<<<Hn * (Dn / 64), 256, 0, stream>>>(W, a_src, a_dst, WP);
    k_proj<<<Bn * (Nn / 16), 256, 0, stream>>>(X, WP, adj, hP, e_src, e_dst, (unsigned*)adjp);
    k_attn<<<Bn * (Nn / 16), 512, 0, stream>>>(adjp, e_src, e_dst, hP, bias, gamma, beta, out);
}